// Round 5
// baseline (853.042 us; speedup 1.0000x reference)
//
#include <hip/hip_runtime.h>
#include <hip/hip_fp16.h>
#include <stdint.h>

#define Bn 8
#define Dd 512
#define Nn 2048

typedef _Float16 f16;
typedef __attribute__((ext_vector_type(8))) _Float16 f16x8;
typedef __attribute__((ext_vector_type(4))) _Float16 f16x4;
typedef __attribute__((ext_vector_type(4))) float f32x4;

// ---- workspace layout (f16 elements) ----
#define OFF_W    ((size_t)0)                       // 3 * 262144 (W as single f16)
#define OFF_XTH  ((size_t)786432)                  // x^T hi, [B][N][D]
#define OFF_XTL  ((size_t)(786432 + 1*8388608))    // x^T lo
#define OFF_Q    ((size_t)(786432 + 2*8388608))    // Q single f16 [B][N][D]
#define OFF_KH   ((size_t)(786432 + 3*8388608))    // K hi [B][N][D]
#define OFF_KL   ((size_t)(786432 + 4*8388608))    // K lo
#define OFF_VT   ((size_t)(786432 + 5*8388608))    // V^T single f16 [B][D][N]
#define OFF_END  ((size_t)(786432 + 6*8388608))    // splitK partials after

static __device__ __forceinline__ f32x4 MFMA16(f16x8 a, f16x8 b, f32x4 c) {
  return __builtin_amdgcn_mfma_f32_16x16x32_f16(a, b, c, 0, 0, 0);
}

// async global->LDS, 16B/lane; lds dest = wave-uniform base + lane*16
static __device__ __forceinline__ void gl16(const f16* g, f16* l) {
  __builtin_amdgcn_global_load_lds(
      (const __attribute__((address_space(1))) void*)(const void*)g,
      (__attribute__((address_space(3))) void*)(void*)l, 16, 0, 0);
}

// ---------------------------------------------------------------------------
__global__ void wcvt_kernel(const float* __restrict__ Wq,
                            const float* __restrict__ Wk,
                            const float* __restrict__ Wv,
                            f16* __restrict__ ws) {
  int idx = blockIdx.x * 256 + threadIdx.x;  // < 786432
  int p = idx >> 18;
  int e = idx & 262143;
  const float* W = (p == 0) ? Wq : ((p == 1) ? Wk : Wv);
  ws[OFF_W + idx] = (f16)W[e];
}

// ---------------------------------------------------------------------------
__global__ void xtsplit_kernel(const float* __restrict__ x,
                               f16* __restrict__ ws) {
  __shared__ float t[32][33];
  int b = blockIdx.z, d0 = blockIdx.y * 32, n0 = blockIdx.x * 32;
  int tid = threadIdx.x;
  int r = tid >> 5, c = tid & 31;
  const float* xb = x + (size_t)b * Dd * Nn;
#pragma unroll
  for (int rr = 0; rr < 4; ++rr) {
    int dl = rr * 8 + r;
    t[dl][c] = xb[(size_t)(d0 + dl) * Nn + n0 + c];
  }
  __syncthreads();
  f16* xh = ws + OFF_XTH + (size_t)b * Nn * Dd;
  f16* xl = ws + OFF_XTL + (size_t)b * Nn * Dd;
#pragma unroll
  for (int rr = 0; rr < 4; ++rr) {
    int nl = rr * 8 + r;
    float v = t[c][nl];
    f16 h = (f16)v;
    int idx = (n0 + nl) * Dd + d0 + c;
    xh[idx] = h;
    xl[idx] = (f16)(v - (float)h);
  }
}

// ---------------------------------------------------------------------------
// k1: projection GEMM, 2-pass f16-split: y = xh*W + xl*W + b.
__global__ __launch_bounds__(256, 2) void proj_kernel(
    f16* __restrict__ ws,
    const float* __restrict__ bq, const float* __restrict__ bk,
    const float* __restrict__ bv) {
  int z = blockIdx.z, b = blockIdx.y, n0 = blockIdx.x * 64;
  const f16* Wp = ws + OFF_W + (size_t)z * 262144;
  const f16* xh = ws + OFF_XTH + (size_t)b * Nn * Dd;
  const f16* xl = ws + OFF_XTL + (size_t)b * Nn * Dd;
  int tid = threadIdx.x;
  int w = tid >> 6, l = tid & 63;
  int l16 = l & 15, lq = l >> 4;
  int j0 = w * 128;

  f32x4 acc[32];
#pragma unroll
  for (int i = 0; i < 32; ++i) acc[i] = (f32x4){0.f, 0.f, 0.f, 0.f};

  for (int ks = 0; ks < 16; ++ks) {
    f16x8 ah[4], al[4], bw[8];
#pragma unroll
    for (int rt = 0; rt < 4; ++rt) {
      int off = (n0 + rt * 16 + l16) * Dd + ks * 32 + lq * 8;
      ah[rt] = *(const f16x8*)(xh + off);
      al[rt] = *(const f16x8*)(xl + off);
    }
#pragma unroll
    for (int ct = 0; ct < 8; ++ct) {
      int woff = (j0 + ct * 16 + l16) * Dd + ks * 32 + lq * 8;
      bw[ct] = *(const f16x8*)(Wp + woff);
    }
#pragma unroll
    for (int ct = 0; ct < 8; ++ct)
#pragma unroll
      for (int rt = 0; rt < 4; ++rt)
        acc[rt * 8 + ct] = MFMA16(ah[rt], bw[ct], acc[rt * 8 + ct]);
#pragma unroll
    for (int ct = 0; ct < 8; ++ct)
#pragma unroll
      for (int rt = 0; rt < 4; ++rt)
        acc[rt * 8 + ct] = MFMA16(al[rt], bw[ct], acc[rt * 8 + ct]);
  }

  const float* bias = (z == 0) ? bq : ((z == 1) ? bk : bv);
  if (z == 0) {
    f16* Qp = ws + OFF_Q + (size_t)b * Nn * Dd;
#pragma unroll
    for (int ct = 0; ct < 8; ++ct) {
      int j = j0 + ct * 16 + l16;
      float bj = bias[j];
#pragma unroll
      for (int rt = 0; rt < 4; ++rt) {
        f32x4 a = acc[rt * 8 + ct];
#pragma unroll
        for (int r = 0; r < 4; ++r)
          Qp[(n0 + rt * 16 + lq * 4 + r) * Dd + j] = (f16)(a[r] + bj);
      }
    }
  } else if (z == 1) {
    f16* Oh = ws + OFF_KH + (size_t)b * Nn * Dd;
    f16* Ol = ws + OFF_KL + (size_t)b * Nn * Dd;
#pragma unroll
    for (int ct = 0; ct < 8; ++ct) {
      int j = j0 + ct * 16 + l16;
      float bj = bias[j];
#pragma unroll
      for (int rt = 0; rt < 4; ++rt) {
        f32x4 a = acc[rt * 8 + ct];
#pragma unroll
        for (int r = 0; r < 4; ++r) {
          float v = a[r] + bj;
          f16 h = (f16)v;
          int n = n0 + rt * 16 + lq * 4 + r;
          Oh[n * Dd + j] = h;
          Ol[n * Dd + j] = (f16)(v - (float)h);
        }
      }
    }
  } else {
    f16* Vt = ws + OFF_VT + (size_t)b * Dd * Nn;
#pragma unroll
    for (int ct = 0; ct < 8; ++ct) {
      int j = j0 + ct * 16 + l16;
      float bj = bias[j];
#pragma unroll
      for (int rt = 0; rt < 4; ++rt) {
        f32x4 a = acc[rt * 8 + ct];
        f16x4 hv;
#pragma unroll
        for (int r = 0; r < 4; ++r) hv[r] = (f16)(a[r] + bj);
        int nb = n0 + rt * 16 + lq * 4;
        *(f16x4*)(Vt + (size_t)j * Nn + nb) = hv;
      }
    }
  }
}

// ---------------------------------------------------------------------------
// k2: split-K flash attention, 4 waves x 16 q-rows = 64 q-rows/block.
// Grid 256*S (1D); XCD swizzle co-locates the 32 blocks sharing one (b,sp)
// K/V slice on one XCD (slice L2-resident). K staged hi+lo in 128-d chunks,
// DOUBLE-BUFFERED via global_load_lds: per phase {stage(p+1); MFMA(p); sync}.
// V read direct from global (L2-hit). P per-wave-private. 4 barriers/kt.
// LDS f16 elems: Kbuf[2][16384] @0 (each: KH[64][128] + KL[64][128]),
// P @32768 (4 waves x 16 x 72 = 4608). Total 37376 f16 = 74752 B -> 2 blk/CU.
#define P_O 32768

__global__ __launch_bounds__(256, 2) void attn_kernel(
    const f16* __restrict__ ws, f16* __restrict__ opart,
    float* __restrict__ mbuf, float* __restrict__ lbuf, int nkt, int lgS) {
  __shared__ f16 lds[37376];
  const int S = 1 << lgS;
  const int cpx = gridDim.x >> 3;
  const int orig = blockIdx.x;
  const int lid = (orig & 7) * cpx + (orig >> 3);
  const int group = lid >> 5, tile = lid & 31;
  const int b = group >> lgS, sp = group & (S - 1);
  const int n0 = tile * 64;

  const int tid = threadIdx.x;
  const int w = tid >> 6, l = tid & 63;
  const int l16 = l & 15, lq = l >> 4;

  const f16* Q  = ws + OFF_Q  + (size_t)b * Nn * Dd;
  const f16* Kh = ws + OFF_KH + (size_t)b * Nn * Dd;
  const f16* Kl = ws + OFF_KL + (size_t)b * Nn * Dd;
  const f16* Vt = ws + OFF_VT + (size_t)b * Dd * Nn;
  const int qrow = n0 + w * 16 + l16;
  const int kbase = sp * nkt * 64;

  // Q held in regs: 16 x f16x8
  f16x8 q[16];
#pragma unroll
  for (int ks = 0; ks < 16; ++ks)
    q[ks] = *(const f16x8*)(Q + (size_t)qrow * Dd + ks * 32 + lq * 8);

  f32x4 o[32];
#pragma unroll
  for (int i = 0; i < 32; ++i) o[i] = (f32x4){0.f, 0.f, 0.f, 0.f};
  float m[4], lsum[4];
#pragma unroll
  for (int r = 0; r < 4; ++r) { m[r] = -1e30f; lsum[r] = 0.f; }

  const int PTOT = nkt * 4;

  // stage(pglob): chunk (kt = pglob>>2, dc = pglob&3) -> buf[pglob&1]
#define STAGE(pglob)                                                         \
  {                                                                          \
    const int kt2 = (pglob) >> 2, dc2 = (pglob) & 3;                         \
    const int k0s = kbase + kt2 * 64;                                        \
    const int bufb = ((pglob) & 1) << 14;                                    \
    _Pragma("unroll") for (int j = 0; j < 8; ++j) {                          \
      const int slot0 = j * 256 + w * 64; /* wave-uniform, 64-aligned */     \
      const int plane = slot0 >> 10;                                         \
      const int s10_0 = slot0 & 1023;                                        \
      const int s10 = s10_0 + l;                                             \
      const int row = s10 >> 4, c = s10 & 15;                                \
      const f16* src = (plane ? Kl : Kh) + (size_t)(k0s + row) * Dd +        \
                       dc2 * 128 + ((c ^ (row & 7)) << 3);                   \
      gl16(src, (f16*)&lds[bufb + plane * 8192 + s10_0 * 8]);                \
    }                                                                        \
  }

  STAGE(0);
  __syncthreads();

  for (int kt = 0; kt < nkt; ++kt) {
    const int k0 = kbase + kt * 64;
    f32x4 s4[4];
#pragma unroll
    for (int ct = 0; ct < 4; ++ct) s4[ct] = (f32x4){0.f, 0.f, 0.f, 0.f};

#pragma unroll
    for (int dc = 0; dc < 4; ++dc) {
      const int p = kt * 4 + dc;
      if (p + 1 < PTOT) STAGE(p + 1);
      const int bufb = (p & 1) << 14;
#pragma unroll
      for (int ks = 0; ks < 4; ++ks) {
        const int ksq = dc * 4 + ks;
        const int cs = ks * 4 + lq;
        f16x8 kb[4];
#pragma unroll
        for (int ct = 0; ct < 4; ++ct) {
          const int row = ct * 16 + l16;
          kb[ct] =
              *(const f16x8*)&lds[bufb + row * 128 + ((cs ^ (row & 7)) << 3)];
        }
#pragma unroll
        for (int ct = 0; ct < 4; ++ct) s4[ct] = MFMA16(q[ksq], kb[ct], s4[ct]);
#pragma unroll
        for (int ct = 0; ct < 4; ++ct) {
          const int row = ct * 16 + l16;
          kb[ct] = *(const f16x8*)&lds[bufb + 8192 + row * 128 +
                                       ((cs ^ (row & 7)) << 3)];
        }
#pragma unroll
        for (int ct = 0; ct < 4; ++ct) s4[ct] = MFMA16(q[ksq], kb[ct], s4[ct]);
      }
      __syncthreads();  // drains stage(p+1); separates phases
    }

    // ---- online softmax (rows live across 16-lane groups)
    float scl[4];
#pragma unroll
    for (int r = 0; r < 4; ++r) {
      float tm = fmaxf(fmaxf(s4[0][r], s4[1][r]), fmaxf(s4[2][r], s4[3][r]));
      tm = fmaxf(tm, __shfl_xor(tm, 1, 16));
      tm = fmaxf(tm, __shfl_xor(tm, 2, 16));
      tm = fmaxf(tm, __shfl_xor(tm, 4, 16));
      tm = fmaxf(tm, __shfl_xor(tm, 8, 16));
      float mn = fmaxf(m[r], tm);
      scl[r] = __expf(m[r] - mn);
      float ps = 0.f;
#pragma unroll
      for (int ct = 0; ct < 4; ++ct) {
        float p2 = __expf(s4[ct][r] - mn);
        s4[ct][r] = p2;
        ps += p2;
      }
      ps += __shfl_xor(ps, 1, 16);
      ps += __shfl_xor(ps, 2, 16);
      ps += __shfl_xor(ps, 4, 16);
      ps += __shfl_xor(ps, 8, 16);
      lsum[r] = lsum[r] * scl[r] + ps;
      m[r] = mn;
    }
#pragma unroll
    for (int i = 0; i < 32; ++i) {
      f32x4 t = o[i];
      t[0] *= scl[0]; t[1] *= scl[1]; t[2] *= scl[2]; t[3] *= scl[3];
      o[i] = t;
    }
    // P -> per-wave-private LDS (no barrier; same-wave lgkmcnt only)
#pragma unroll
    for (int ct = 0; ct < 4; ++ct)
#pragma unroll
      for (int r = 0; r < 4; ++r)
        lds[P_O + w * 1152 + (lq * 4 + r) * 72 + ct * 16 + l16] =
            (f16)s4[ct][r];
    asm volatile("s_waitcnt lgkmcnt(0)" ::: "memory");

    // ---- PV: O += P V, V direct from global (L2-resident via colocation)
#pragma unroll
    for (int kks = 0; kks < 2; ++kks) {
      f16x8 pa =
          *(const f16x8*)&lds[P_O + w * 1152 + l16 * 72 + kks * 32 + lq * 8];
#pragma unroll
      for (int i = 0; i < 32; ++i) {
        const int d = i * 16 + l16;
        f16x8 vb =
            *(const f16x8*)(Vt + (size_t)d * Nn + k0 + kks * 32 + lq * 8);
        o[i] = MFMA16(pa, vb, o[i]);
      }
    }
  }

  // ---- epilogue: transpose O through LDS (stride-72 rows) for coalesced
  // full-line writes of opart[sp][b][d][n0..n0+63] (f16), plus m,l.
  if (l16 == 0) {
    size_t msl = ((size_t)sp * Bn + b) * Nn;
    const int nbase = n0 + w * 16 + lq * 4;
#pragma unroll
    for (int r = 0; r < 4; ++r) {
      mbuf[msl + nbase + r] = m[r];
      lbuf[msl + nbase + r] = lsum[r];
    }
  }
  __syncthreads();  // K/P regions dead; reuse all LDS for O staging
  {
    const int nloc = w * 16 + lq * 4;
#pragma unroll
    for (int i = 0; i < 32; ++i) {
      const int d = i * 16 + l16;
      f16x4 hv;
#pragma unroll
      for (int r = 0; r < 4; ++r) hv[r] = (f16)o[i][r];
      *(f16x4*)&lds[d * 72 + nloc] = hv;
    }
  }
  __syncthreads();
  {
    f16* opb = opart + ((size_t)sp * Bn + b) * Dd * Nn;
    const int c8 = tid & 7;
#pragma unroll
    for (int it = 0; it < 16; ++it) {
      const int row = it * 32 + (tid >> 3);
      f16x8 v = *(const f16x8*)&lds[row * 72 + c8 * 8];
      *(f16x8*)(opb + (size_t)row * Nn + n0 + c8 * 8) = v;
    }
  }
#undef STAGE
}

// ---------------------------------------------------------------------------
template <int S>
__global__ __launch_bounds__(256) void merge_kernel(
    const f16* __restrict__ opart, const float* __restrict__ mbuf,
    const float* __restrict__ lbuf, float* __restrict__ out) {
  int idx = blockIdx.x * 256 + threadIdx.x;   // < B*D*N/8
  int nb = (idx & 255) * 8;
  int d = (idx >> 8) & 511;
  int b = idx >> 17;

  float ms[4][8], ls[4][8];
#pragma unroll
  for (int s = 0; s < S; ++s) {
    const float* mp = mbuf + ((size_t)s * Bn + b) * Nn + nb;
    const float* lp = lbuf + ((size_t)s * Bn + b) * Nn + nb;
    f32x4 a0 = *(const f32x4*)mp, a1 = *(const f32x4*)(mp + 4);
    f32x4 c0 = *(const f32x4*)lp, c1 = *(const f32x4*)(lp + 4);
#pragma unroll
    for (int j = 0; j < 4; ++j) {
      ms[s][j] = a0[j]; ms[s][4 + j] = a1[j];
      ls[s][j] = c0[j]; ls[s][4 + j] = c1[j];
    }
  }
  float M[8], den[8], acc[8];
#pragma unroll
  for (int j = 0; j < 8; ++j) M[j] = ms[0][j];
#pragma unroll
  for (int s = 1; s < S; ++s)
#pragma unroll
    for (int j = 0; j < 8; ++j) M[j] = fmaxf(M[j], ms[s][j]);
#pragma unroll
  for (int j = 0; j < 8; ++j) { den[j] = 0.f; acc[j] = 0.f; }
#pragma unroll
  for (int s = 0; s < S; ++s) {
    const f16* op = opart + (((size_t)s * Bn + b) * Dd + d) * Nn + nb;
    f16x8 ov = *(const f16x8*)op;
#pragma unroll
    for (int j = 0; j < 8; ++j) {
      float wgt = __expf(ms[s][j] - M[j]);
      den[j] += ls[s][j] * wgt;
      acc[j] += (float)ov[j] * wgt;
    }
  }
  float* po = out + ((size_t)b * Dd + d) * Nn + nb;
  f32x4 r0, r1;
#pragma unroll
  for (int j = 0; j < 4; ++j) {
    r0[j] = acc[j] / den[j];
    r1[j] = acc[4 + j] / den[4 + j];
  }
  *(f32x4*)po = r0;
  *(f32x4*)(po + 4) = r1;
}

// ---------------------------------------------------------------------------
extern "C" void kernel_launch(void* const* d_in, const int* in_sizes, int n_in,
                              void* d_out, int out_size, void* d_ws,
                              size_t ws_size, hipStream_t stream) {
  const float* x  = (const float*)d_in[0];
  const float* Wq = (const float*)d_in[1];
  const float* bq = (const float*)d_in[2];
  const float* Wk = (const float*)d_in[3];
  const float* bk = (const float*)d_in[4];
  const float* Wv = (const float*)d_in[5];
  const float* bv = (const float*)d_in[6];
  f16* ws = (f16*)d_ws;
  float* out = (float*)d_out;

  int S = 1, lgS = 0;
  {
    size_t need4 = (OFF_END + 4ull * 8388608) * 2 + 4ull * 131072;
    size_t need2 = (OFF_END + 2ull * 8388608) * 2 + 2ull * 131072;
    if (ws_size >= need4) { S = 4; lgS = 2; }
    else if (ws_size >= need2) { S = 2; lgS = 1; }
  }
  f16* opart = ws + OFF_END;
  float* mbuf = (float*)(opart + (size_t)S * 8388608);
  float* lbuf = mbuf + (size_t)S * Bn * Nn;

  hipLaunchKernelGGL(wcvt_kernel, dim3(3072), dim3(256), 0, stream,
                     Wq, Wk, Wv, ws);
  hipLaunchKernelGGL(xtsplit_kernel, dim3(Nn / 32, Dd / 32, Bn), dim3(256), 0,
                     stream, x, ws);
  hipLaunchKernelGGL(proj_kernel, dim3(Nn / 64, Bn, 3), dim3(256), 0, stream,
                     ws, bq, bk, bv);
  hipLaunchKernelGGL(attn_kernel, dim3(256 * S), dim3(256), 0, stream,
                     ws, opart, mbuf, lbuf, 32 / S, lgS);
  switch (S) {
    case 4:
      hipLaunchKernelGGL((merge_kernel<4>), dim3(4096), dim3(256), 0, stream,
                         opart, mbuf, lbuf, out);
      break;
    case 2:
      hipLaunchKernelGGL((merge_kernel<2>), dim3(4096), dim3(256), 0, stream,
                         opart, mbuf, lbuf, out);
      break;
    default:
      hipLaunchKernelGGL((merge_kernel<1>), dim3(4096), dim3(256), 0, stream,
                         opart, mbuf, lbuf, out);
      break;
  }
}

// Round 6
// 535.504 us; speedup vs baseline: 1.5930x; 1.5930x over previous
//
#include <hip/hip_runtime.h>
#include <hip/hip_fp16.h>
#include <stdint.h>

#define Bn 8
#define Dd 512
#define Nn 2048

typedef _Float16 f16;
typedef __attribute__((ext_vector_type(8))) _Float16 f16x8;
typedef __attribute__((ext_vector_type(4))) _Float16 f16x4;
typedef __attribute__((ext_vector_type(4))) float f32x4;

// ---- workspace layout (f16 elements), all single-plane f16 ----
#define OFF_W   ((size_t)0)                        // 3 * 262144
#define OFF_XT  ((size_t)786432)                   // x^T [B][N][D]
#define OFF_Q   ((size_t)(786432 + 1*8388608))     // Q [B][N][D]
#define OFF_K   ((size_t)(786432 + 2*8388608))     // K [B][N][D]
#define OFF_VT  ((size_t)(786432 + 3*8388608))     // V^T [B][D][N]
#define OFF_OP  ((size_t)(786432 + 4*8388608))     // opart [S][B][D][N]

static __device__ __forceinline__ f32x4 MFMA16(f16x8 a, f16x8 b, f32x4 c) {
  return __builtin_amdgcn_mfma_f32_16x16x32_f16(a, b, c, 0, 0, 0);
}

// async global->LDS, 16B/lane; lds dest = wave-uniform base + lane*16
static __device__ __forceinline__ void gl16(const f16* g, f16* l) {
  __builtin_amdgcn_global_load_lds(
      (const __attribute__((address_space(1))) void*)(const void*)g,
      (__attribute__((address_space(3))) void*)(void*)l, 16, 0, 0);
}

#define WAITV(n) asm volatile("s_waitcnt vmcnt(" #n ")" ::: "memory")

// ---------------------------------------------------------------------------
__global__ void wcvt_kernel(const float* __restrict__ Wq,
                            const float* __restrict__ Wk,
                            const float* __restrict__ Wv,
                            f16* __restrict__ ws) {
  int idx = blockIdx.x * 256 + threadIdx.x;  // < 786432
  int p = idx >> 18;
  int e = idx & 262143;
  const float* W = (p == 0) ? Wq : ((p == 1) ? Wk : Wv);
  ws[OFF_W + idx] = (f16)W[e];
}

// ---------------------------------------------------------------------------
// transpose x [B][D][N] -> xt [B][N][D], single f16
__global__ void xt_kernel(const float* __restrict__ x, f16* __restrict__ ws) {
  __shared__ float t[32][33];
  int b = blockIdx.z, d0 = blockIdx.y * 32, n0 = blockIdx.x * 32;
  int tid = threadIdx.x;
  int r = tid >> 5, c = tid & 31;
  const float* xb = x + (size_t)b * Dd * Nn;
#pragma unroll
  for (int rr = 0; rr < 4; ++rr) {
    int dl = rr * 8 + r;
    t[dl][c] = xb[(size_t)(d0 + dl) * Nn + n0 + c];
  }
  __syncthreads();
  f16* xt = ws + OFF_XT + (size_t)b * Nn * Dd;
#pragma unroll
  for (int rr = 0; rr < 4; ++rr) {
    int nl = rr * 8 + r;
    xt[(n0 + nl) * Dd + d0 + c] = (f16)t[c][nl];
  }
}

// ---------------------------------------------------------------------------
// projection GEMM, single-pass f16: y = xt*W^T + b. grid (N/64, B, 3).
__global__ __launch_bounds__(256, 2) void proj_kernel(
    f16* __restrict__ ws,
    const float* __restrict__ bq, const float* __restrict__ bk,
    const float* __restrict__ bv) {
  int z = blockIdx.z, b = blockIdx.y, n0 = blockIdx.x * 64;
  const f16* Wp = ws + OFF_W + (size_t)z * 262144;
  const f16* xt = ws + OFF_XT + (size_t)b * Nn * Dd;
  int tid = threadIdx.x;
  int w = tid >> 6, l = tid & 63;
  int l16 = l & 15, lq = l >> 4;
  int j0 = w * 128;

  f32x4 acc[32];
#pragma unroll
  for (int i = 0; i < 32; ++i) acc[i] = (f32x4){0.f, 0.f, 0.f, 0.f};

  for (int ks = 0; ks < 16; ++ks) {
    f16x8 ax[4], bw[8];
#pragma unroll
    for (int rt = 0; rt < 4; ++rt)
      ax[rt] = *(const f16x8*)(xt + (n0 + rt * 16 + l16) * Dd + ks * 32 + lq * 8);
#pragma unroll
    for (int ct = 0; ct < 8; ++ct)
      bw[ct] = *(const f16x8*)(Wp + (j0 + ct * 16 + l16) * Dd + ks * 32 + lq * 8);
#pragma unroll
    for (int ct = 0; ct < 8; ++ct)
#pragma unroll
      for (int rt = 0; rt < 4; ++rt)
        acc[rt * 8 + ct] = MFMA16(ax[rt], bw[ct], acc[rt * 8 + ct]);
  }

  const float* bias = (z == 0) ? bq : ((z == 1) ? bk : bv);
  if (z < 2) {
    f16* Op = ws + ((z == 0) ? OFF_Q : OFF_K) + (size_t)b * Nn * Dd;
#pragma unroll
    for (int ct = 0; ct < 8; ++ct) {
      int j = j0 + ct * 16 + l16;
      float bj = bias[j];
#pragma unroll
      for (int rt = 0; rt < 4; ++rt) {
        f32x4 a = acc[rt * 8 + ct];
#pragma unroll
        for (int r = 0; r < 4; ++r)
          Op[(n0 + rt * 16 + lq * 4 + r) * Dd + j] = (f16)(a[r] + bj);
      }
    }
  } else {
    f16* Vt = ws + OFF_VT + (size_t)b * Dd * Nn;
#pragma unroll
    for (int ct = 0; ct < 8; ++ct) {
      int j = j0 + ct * 16 + l16;
      float bj = bias[j];
#pragma unroll
      for (int rt = 0; rt < 4; ++rt) {
        f32x4 a = acc[rt * 8 + ct];
        f16x4 hv;
#pragma unroll
        for (int r = 0; r < 4; ++r) hv[r] = (f16)(a[r] + bj);
        *(f16x4*)(Vt + (size_t)j * Nn + n0 + rt * 16 + lq * 4) = hv;
      }
    }
  }
}

// ---------------------------------------------------------------------------
// split-K flash attention, 8 waves x 16 q-rows = 128 q-rows/block.
// Grid 128*S (1D), XCD swizzle: 16 blocks sharing a (b,sp) K/V slice are
// contiguous -> co-resident on one XCD, slice L2-resident.
// Counted-vmcnt pipeline (T3+T4): K chunks [64 keys][128 d] double-buffered,
// V [512][64] staged during previous PV. Loads stay in flight across raw
// s_barriers; per-phase waits vmcnt(10,10,2,2); V force-drained at p2.
// LDS f16: Kbuf[2][8192] @0, V @16384 (32768), P @49152 (8*16*72).
// Total 58368 f16 = 116736 B -> 1 block (8 waves) per CU.
#define VO 16384
#define PO 49152

__global__ __launch_bounds__(512, 2) void attn_kernel(
    const f16* __restrict__ ws, f16* __restrict__ opart,
    float* __restrict__ mbuf, float* __restrict__ lbuf, int nkt, int lgS) {
  __shared__ f16 lds[58368];
  const int S = 1 << lgS;
  const int cpx = gridDim.x >> 3;
  const int orig = blockIdx.x;
  const int lid = (orig & 7) * cpx + (orig >> 3);
  const int group = lid >> 4, tile = lid & 15;
  const int b = group >> lgS, sp = group & (S - 1);
  const int n0 = tile * 128;

  const int tid = threadIdx.x;
  const int w = tid >> 6, l = tid & 63;
  const int l16 = l & 15, lq = l >> 4;

  const f16* Q  = ws + OFF_Q  + (size_t)b * Nn * Dd;
  const f16* Kp = ws + OFF_K  + (size_t)b * Nn * Dd;
  const f16* Vt = ws + OFF_VT + (size_t)b * Dd * Nn;
  const int qrow = n0 + w * 16 + l16;
  const int kbase = sp * nkt * 64;

  // K chunk stage: 64 rows x 128 d = 1024 x 16B slots, 2/thread
#define KSTAGE(kt_, dc_, bb_)                                               \
  {                                                                         \
    const int k0s = kbase + (kt_) * 64;                                     \
    _Pragma("unroll") for (int j = 0; j < 2; ++j) {                         \
      const int slot0 = j * 512 + w * 64;                                   \
      const int slot = slot0 + l;                                           \
      const int row = slot >> 4, c = slot & 15;                             \
      const f16* src = Kp + (size_t)(k0s + row) * Dd + (dc_) * 128 +        \
                       ((c ^ (row & 7)) << 3);                              \
      gl16(src, (f16*)&lds[(bb_) * 8192 + slot0 * 8]);                      \
    }                                                                       \
  }
  // V stage: 512 rows x 64 keys = 4096 slots, 8/thread
#define VSTAGE(kt_)                                                         \
  {                                                                         \
    const int k0s = kbase + (kt_) * 64;                                     \
    _Pragma("unroll") for (int j = 0; j < 8; ++j) {                         \
      const int slot0 = j * 512 + w * 64;                                   \
      const int slot = slot0 + l;                                           \
      const int d = slot >> 3, c = slot & 7;                                \
      const f16* src = Vt + (size_t)d * Nn + k0s + ((c ^ (d & 7)) << 3);    \
      gl16(src, (f16*)&lds[VO + slot0 * 8]);                                \
    }                                                                       \
  }
  // QK^T on a 128-d chunk from Kbuf[bb_]
#define QKT(dc_, bb_)                                                       \
  _Pragma("unroll") for (int ks = 0; ks < 4; ++ks) {                        \
    const int swz = (((ks * 4 + lq) ^ (l16 & 7)) << 3);                     \
    f16x8 kb0 = *(const f16x8*)&lds[(bb_) * 8192 + (l16) * 128 + swz];      \
    f16x8 kb1 = *(const f16x8*)&lds[(bb_) * 8192 + (16 + l16) * 128 + swz]; \
    f16x8 kb2 = *(const f16x8*)&lds[(bb_) * 8192 + (32 + l16) * 128 + swz]; \
    f16x8 kb3 = *(const f16x8*)&lds[(bb_) * 8192 + (48 + l16) * 128 + swz]; \
    s4[0] = MFMA16(q[(dc_) * 4 + ks], kb0, s4[0]);                          \
    s4[1] = MFMA16(q[(dc_) * 4 + ks], kb1, s4[1]);                          \
    s4[2] = MFMA16(q[(dc_) * 4 + ks], kb2, s4[2]);                          \
    s4[3] = MFMA16(q[(dc_) * 4 + ks], kb3, s4[3]);                          \
  }

  // Q held in regs
  f16x8 q[16];
#pragma unroll
  for (int ks = 0; ks < 16; ++ks)
    q[ks] = *(const f16x8*)(Q + (size_t)qrow * Dd + ks * 32 + lq * 8);

  f32x4 o[32];
#pragma unroll
  for (int i = 0; i < 32; ++i) o[i] = (f32x4){0.f, 0.f, 0.f, 0.f};
  float m[4], lsum[4];
#pragma unroll
  for (int r = 0; r < 4; ++r) { m[r] = -1e30f; lsum[r] = 0.f; }

  // prologue: issue order [K0(2), K1(2), V(8)] = 12 outstanding
  KSTAGE(0, 0, 0);
  KSTAGE(0, 1, 1);
  VSTAGE(0);

  for (int kt = 0; kt < nkt; ++kt) {
    const int ktn = (kt + 1 < nkt) ? kt + 1 : kt;  // uniform ledger on last
    f32x4 s4[4];
#pragma unroll
    for (int ct = 0; ct < 4; ++ct) s4[ct] = (f32x4){0.f, 0.f, 0.f, 0.f};

    // ---- 4 QK^T phases; ledger (outstanding oldest->newest at each wait):
    // p0:[K0 2,K1 2,V 8] w10 | p1:[K1 2,V 8,K2 2] w10 | p2:[V 8,K2 2,K3 2] w2
    // p3:[K3 2,Kn0 2] w2
    WAITV(10);
    __builtin_amdgcn_s_barrier();
    QKT(0, 0);
    __builtin_amdgcn_s_barrier();
    KSTAGE(kt, 2, 0);

    WAITV(10);
    __builtin_amdgcn_s_barrier();
    QKT(1, 1);
    __builtin_amdgcn_s_barrier();
    KSTAGE(kt, 3, 1);

    WAITV(2);  // drains V(kt) too (older than K2) — needed by PV anyway
    __builtin_amdgcn_s_barrier();
    QKT(2, 0);
    __builtin_amdgcn_s_barrier();
    KSTAGE(ktn, 0, 0);

    WAITV(2);
    __builtin_amdgcn_s_barrier();
    QKT(3, 1);
    __builtin_amdgcn_s_barrier();
    KSTAGE(ktn, 1, 1);

    // ---- online softmax (rows live across 16-lane groups)
    float scl[4];
#pragma unroll
    for (int r = 0; r < 4; ++r) {
      float tm = fmaxf(fmaxf(s4[0][r], s4[1][r]), fmaxf(s4[2][r], s4[3][r]));
      tm = fmaxf(tm, __shfl_xor(tm, 1, 16));
      tm = fmaxf(tm, __shfl_xor(tm, 2, 16));
      tm = fmaxf(tm, __shfl_xor(tm, 4, 16));
      tm = fmaxf(tm, __shfl_xor(tm, 8, 16));
      float mn = fmaxf(m[r], tm);
      scl[r] = __expf(m[r] - mn);
      float ps = 0.f;
#pragma unroll
      for (int ct = 0; ct < 4; ++ct) {
        float p2 = __expf(s4[ct][r] - mn);
        s4[ct][r] = p2;
        ps += p2;
      }
      ps += __shfl_xor(ps, 1, 16);
      ps += __shfl_xor(ps, 2, 16);
      ps += __shfl_xor(ps, 4, 16);
      ps += __shfl_xor(ps, 8, 16);
      lsum[r] = lsum[r] * scl[r] + ps;
      m[r] = mn;
    }
#pragma unroll
    for (int i = 0; i < 32; ++i) {
      f32x4 t = o[i];
      t[0] *= scl[0]; t[1] *= scl[1]; t[2] *= scl[2]; t[3] *= scl[3];
      o[i] = t;
    }
    // P -> per-wave-private LDS (same-wave visibility via lgkmcnt only)
#pragma unroll
    for (int ct = 0; ct < 4; ++ct)
#pragma unroll
      for (int r = 0; r < 4; ++r)
        lds[PO + w * 1152 + (lq * 4 + r) * 72 + ct * 16 + l16] =
            (f16)s4[ct][r];
    asm volatile("s_waitcnt lgkmcnt(0)" ::: "memory");

    // ---- PV from LDS V (V(kt) guaranteed landed at p2 wait + barrier)
#pragma unroll
    for (int kks = 0; kks < 2; ++kks) {
      f16x8 pa =
          *(const f16x8*)&lds[PO + w * 1152 + l16 * 72 + kks * 32 + lq * 8];
      const int vswz = (((kks * 4 + lq) ^ (l16 & 7)) << 3);
#pragma unroll
      for (int i = 0; i < 32; ++i) {
        f16x8 vb = *(const f16x8*)&lds[VO + (i * 16 + l16) * 64 + vswz];
        o[i] = MFMA16(pa, vb, o[i]);
      }
    }
    __builtin_amdgcn_s_barrier();  // all waves done reading V(kt)
    VSTAGE(ktn);                   // 8 loads -> steady-state ledger
  }

  // ---- epilogue: drain stray stages (they write LDS), then store
  WAITV(0);
  f16* opb = opart + ((size_t)sp * Bn + b) * Dd * Nn;
  const int nbase = n0 + w * 16 + lq * 4;
#pragma unroll
  for (int i = 0; i < 32; ++i) {
    const int d = i * 16 + l16;
    f16x4 hv;
#pragma unroll
    for (int r = 0; r < 4; ++r) hv[r] = (f16)o[i][r];
    *(f16x4*)(opb + (size_t)d * Nn + nbase) = hv;
  }
  if (l16 == 0) {
    size_t msl = ((size_t)sp * Bn + b) * Nn;
#pragma unroll
    for (int r = 0; r < 4; ++r) {
      mbuf[msl + nbase + r] = m[r];
      lbuf[msl + nbase + r] = lsum[r];
    }
  }
#undef KSTAGE
#undef VSTAGE
#undef QKT
}

// ---------------------------------------------------------------------------
template <int S>
__global__ __launch_bounds__(256) void merge_kernel(
    const f16* __restrict__ opart, const float* __restrict__ mbuf,
    const float* __restrict__ lbuf, float* __restrict__ out) {
  int idx = blockIdx.x * 256 + threadIdx.x;   // < B*D*N/8
  int nb = (idx & 255) * 8;
  int d = (idx >> 8) & 511;
  int b = idx >> 17;

  float ms[4][8], ls[4][8];
#pragma unroll
  for (int s = 0; s < S; ++s) {
    const float* mp = mbuf + ((size_t)s * Bn + b) * Nn + nb;
    const float* lp = lbuf + ((size_t)s * Bn + b) * Nn + nb;
    f32x4 a0 = *(const f32x4*)mp, a1 = *(const f32x4*)(mp + 4);
    f32x4 c0 = *(const f32x4*)lp, c1 = *(const f32x4*)(lp + 4);
#pragma unroll
    for (int j = 0; j < 4; ++j) {
      ms[s][j] = a0[j]; ms[s][4 + j] = a1[j];
      ls[s][j] = c0[j]; ls[s][4 + j] = c1[j];
    }
  }
  float M[8], den[8], acc[8];
#pragma unroll
  for (int j = 0; j < 8; ++j) M[j] = ms[0][j];
#pragma unroll
  for (int s = 1; s < S; ++s)
#pragma unroll
    for (int j = 0; j < 8; ++j) M[j] = fmaxf(M[j], ms[s][j]);
#pragma unroll
  for (int j = 0; j < 8; ++j) { den[j] = 0.f; acc[j] = 0.f; }
#pragma unroll
  for (int s = 0; s < S; ++s) {
    const f16* op = opart + (((size_t)s * Bn + b) * Dd + d) * Nn + nb;
    f16x8 ov = *(const f16x8*)op;
#pragma unroll
    for (int j = 0; j < 8; ++j) {
      float wgt = __expf(ms[s][j] - M[j]);
      den[j] += ls[s][j] * wgt;
      acc[j] += (float)ov[j] * wgt;
    }
  }
  float* po = out + ((size_t)b * Dd + d) * Nn + nb;
  f32x4 r0, r1;
#pragma unroll
  for (int j = 0; j < 4; ++j) {
    r0[j] = acc[j] / den[j];
    r1[j] = acc[4 + j] / den[4 + j];
  }
  *(f32x4*)po = r0;
  *(f32x4*)(po + 4) = r1;
}

// ---------------------------------------------------------------------------
extern "C" void kernel_launch(void* const* d_in, const int* in_sizes, int n_in,
                              void* d_out, int out_size, void* d_ws,
                              size_t ws_size, hipStream_t stream) {
  const float* x  = (const float*)d_in[0];
  const float* Wq = (const float*)d_in[1];
  const float* bq = (const float*)d_in[2];
  const float* Wk = (const float*)d_in[3];
  const float* bk = (const float*)d_in[4];
  const float* Wv = (const float*)d_in[5];
  const float* bv = (const float*)d_in[6];
  f16* ws = (f16*)d_ws;
  float* out = (float*)d_out;

  int S = 1, lgS = 0;
  {
    size_t need4 = (OFF_OP + 4ull * 8388608) * 2 + 4ull * 131072;
    size_t need2 = (OFF_OP + 2ull * 8388608) * 2 + 2ull * 131072;
    if (ws_size >= need4) { S = 4; lgS = 2; }
    else if (ws_size >= need2) { S = 2; lgS = 1; }
  }
  f16* opart = ws + OFF_OP;
  float* mbuf = (float*)(opart + (size_t)S * 8388608);
  float* lbuf = mbuf + (size_t)S * Bn * Nn;

  hipLaunchKernelGGL(wcvt_kernel, dim3(3072), dim3(256), 0, stream,
                     Wq, Wk, Wv, ws);
  hipLaunchKernelGGL(xt_kernel, dim3(Nn / 32, Dd / 32, Bn), dim3(256), 0,
                     stream, x, ws);
  hipLaunchKernelGGL(proj_kernel, dim3(Nn / 64, Bn, 3), dim3(256), 0, stream,
                     ws, bq, bk, bv);
  hipLaunchKernelGGL(attn_kernel, dim3(128 * S), dim3(512), 0, stream,
                     ws, opart, mbuf, lbuf, 32 / S, lgS);
  switch (S) {
    case 4:
      hipLaunchKernelGGL((merge_kernel<4>), dim3(4096), dim3(256), 0, stream,
                         opart, mbuf, lbuf, out);
      break;
    case 2:
      hipLaunchKernelGGL((merge_kernel<2>), dim3(4096), dim3(256), 0, stream,
                         opart, mbuf, lbuf, out);
      break;
    default:
      hipLaunchKernelGGL((merge_kernel<1>), dim3(4096), dim3(256), 0, stream,
                         opart, mbuf, lbuf, out);
      break;
  }
}